// Round 3
// baseline (842.999 us; speedup 1.0000x reference)
//
#include <hip/hip_runtime.h>

#define BB 4096
#define SS 128
#define NB 16
#define NT 256
#define CS 32          // timesteps per chunk
#define NCH (SS/CS)    // 4 chunks
#define NSUB 2         // encoder sub-chunks per chunk
#define STEPS_A (CS/NSUB)

typedef __attribute__((ext_vector_type(8))) short short8;
typedef __attribute__((ext_vector_type(4))) float f32x4;
typedef unsigned short ushort_t;
typedef unsigned int uint_t;

#define SX_STR   72
#define SH1_STR  264
#define SEMB_STR 136
#define SH_STR   72

__device__ __forceinline__ ushort_t f2bf(float f) {
    union { float f; unsigned u; } x; x.f = f;
    unsigned r = x.u + 0x7FFFu + ((x.u >> 16) & 1u);
    return (ushort_t)(r >> 16);
}
__device__ __forceinline__ float bf2f(ushort_t h) {
    union { unsigned u; float f; } x; x.u = ((unsigned)h) << 16; return x.f;
}
__device__ __forceinline__ float fsig(float x)  { return 1.f / (1.f + __expf(-x)); }
__device__ __forceinline__ float ftanh(float x) { return 1.f - 2.f / (__expf(2.f * x) + 1.f); }

union FragU { short8 v; ushort_t u[8]; };

// ============================================================================
// Kernel A: encoder. wx[b, s, 256] = relu(relu(x@W1+b1)@W2+b2)@Wih + bih + bhh
// stored bf16 into ws, swizzled per (s_chunk_local, batch_group_16):
//   dword idx = (g4*64 + l)*4 + e, where value dword d = tt*2 + rp = 4*g4+e,
//   tt = gate tile (16 cols), rp = row-pair, l = 16q+m (lane id).
// ============================================================================
__global__ __launch_bounds__(NT, 2)
void podcritic_enc(const float* __restrict__ self_obs,
                   const float* __restrict__ tm_obs,
                   const float* __restrict__ en_obs,
                   const float* __restrict__ cp_obs,
                   const float* __restrict__ W1, const float* __restrict__ b1,
                   const float* __restrict__ W2, const float* __restrict__ b2,
                   const float* __restrict__ Wih, const float* __restrict__ bih,
                   const float* __restrict__ bhh,
                   uint_t* __restrict__ wx, int c0)
{
    __shared__ __align__(16) ushort_t sx[2][NB * SX_STR];
    __shared__ __align__(16) ushort_t sh1[NB * SH1_STR];
    __shared__ __align__(16) ushort_t semb[NB * SEMB_STR];

    const int t  = threadIdx.x;
    const int w  = t >> 6;
    const int l  = t & 63;
    const int q  = l >> 4;
    const int m  = l & 15;
    const int bg = blockIdx.x;
    const int b0 = bg * NB;
    const int sbase = c0 + blockIdx.y * STEPS_A;

    short8 w1f[4][2];
    short8 w2f[2][8];
    short8 wihf[4][4];
    float bias1[4], bias2[2], bgf[4];

    #pragma unroll
    for (int i = 0; i < 4; ++i) {
        int n = w * 64 + i * 16 + m;
        bias1[i] = b1[n];
        #pragma unroll
        for (int kk = 0; kk < 2; ++kk) {
            FragU u;
            #pragma unroll
            for (int j = 0; j < 8; ++j) {
                int k = kk * 32 + q * 8 + j;
                u.u[j] = f2bf(k < 47 ? W1[k * 256 + n] : 0.f);
            }
            w1f[i][kk] = u.v;
        }
    }
    #pragma unroll
    for (int i = 0; i < 2; ++i) {
        int n = 32 * w + i * 16 + m;
        bias2[i] = b2[n];
        #pragma unroll
        for (int kk = 0; kk < 8; ++kk) {
            FragU u;
            #pragma unroll
            for (int j = 0; j < 8; ++j) {
                int k = kk * 32 + q * 8 + j;
                u.u[j] = f2bf(W2[k * 128 + n]);
            }
            w2f[i][kk] = u.v;
        }
    }
    #pragma unroll
    for (int i = 0; i < 4; ++i) {
        int n = (w + 4 * i) * 16 + m;
        bgf[i] = bih[n] + bhh[n];
        #pragma unroll
        for (int kk = 0; kk < 4; ++kk) {
            FragU u;
            #pragma unroll
            for (int j = 0; j < 8; ++j) {
                int k = kk * 32 + q * 8 + j;
                u.u[j] = f2bf(Wih[k * 256 + n]);
            }
            wihf[i][kk] = u.v;
        }
    }

    const int pcol = t & 63;
    const int prow = t >> 6;
    #pragma unroll
    for (int j = 0; j < 4; ++j) {
        int r  = 4 * j + prow;
        int bs = (b0 + r) * SS + sbase;
        float v = 0.f;
        if (pcol < 15)      v = self_obs[bs * 15 + pcol];
        else if (pcol < 28) v = tm_obs[bs * 13 + (pcol - 15)];
        else if (pcol < 41) { int kk = pcol - 28;
                              v = 0.5f * (en_obs[(bs * 2) * 13 + kk] + en_obs[(bs * 2) * 13 + 13 + kk]); }
        else if (pcol < 47) v = cp_obs[bs * 6 + (pcol - 41)];
        sx[0][r * SX_STR + pcol] = f2bf(v);
    }
    __syncthreads();

    int cur = 0;
    for (int sl = 0; sl < STEPS_A; ++sl) {
        const int s = sbase + sl;

        float pf[4];
        #pragma unroll
        for (int j = 0; j < 4; ++j) {
            float v = 0.f;
            if (sl + 1 < STEPS_A) {
                int r  = 4 * j + prow;
                int bs = (b0 + r) * SS + (s + 1);
                if (pcol < 15)      v = self_obs[bs * 15 + pcol];
                else if (pcol < 28) v = tm_obs[bs * 13 + (pcol - 15)];
                else if (pcol < 41) { int kk = pcol - 28;
                                      v = 0.5f * (en_obs[(bs * 2) * 13 + kk] + en_obs[(bs * 2) * 13 + 13 + kk]); }
                else if (pcol < 47) v = cp_obs[bs * 6 + (pcol - 41)];
            }
            pf[j] = v;
        }

        // phase 1: H1
        {
            f32x4 c1[4] = {{0,0,0,0},{0,0,0,0},{0,0,0,0},{0,0,0,0}};
            #pragma unroll
            for (int kk = 0; kk < 2; ++kk) {
                short8 a = *(const short8*)&sx[cur][m * SX_STR + kk * 32 + q * 8];
                #pragma unroll
                for (int i = 0; i < 4; ++i)
                    c1[i] = __builtin_amdgcn_mfma_f32_16x16x32_bf16(a, w1f[i][kk], c1[i], 0, 0, 0);
            }
            #pragma unroll
            for (int i = 0; i < 4; ++i) {
                int col = w * 64 + i * 16 + m;
                #pragma unroll
                for (int r = 0; r < 4; ++r)
                    sh1[(q * 4 + r) * SH1_STR + col] = f2bf(fmaxf(c1[i][r] + bias1[i], 0.f));
            }
        }
        __syncthreads();

        // phase 2: EMB
        {
            f32x4 c2[2] = {{0,0,0,0},{0,0,0,0}};
            #pragma unroll
            for (int kk = 0; kk < 8; ++kk) {
                short8 a = *(const short8*)&sh1[m * SH1_STR + kk * 32 + q * 8];
                #pragma unroll
                for (int i = 0; i < 2; ++i)
                    c2[i] = __builtin_amdgcn_mfma_f32_16x16x32_bf16(a, w2f[i][kk], c2[i], 0, 0, 0);
            }
            #pragma unroll
            for (int i = 0; i < 2; ++i) {
                int col = 32 * w + i * 16 + m;
                #pragma unroll
                for (int r = 0; r < 4; ++r)
                    semb[(q * 4 + r) * SEMB_STR + col] = f2bf(fmaxf(c2[i][r] + bias2[i], 0.f));
            }
        }
        __syncthreads();

        // phase 3: wx = emb@Wih + (bih+bhh), swizzled bf16 store to ws
        {
            f32x4 g[4];
            #pragma unroll
            for (int i = 0; i < 4; ++i) g[i] = (f32x4){bgf[i], bgf[i], bgf[i], bgf[i]};
            #pragma unroll
            for (int kk = 0; kk < 4; ++kk) {
                short8 a = *(const short8*)&semb[m * SEMB_STR + kk * 32 + q * 8];
                #pragma unroll
                for (int i = 0; i < 4; ++i)
                    g[i] = __builtin_amdgcn_mfma_f32_16x16x32_bf16(a, wihf[i][kk], g[i], 0, 0, 0);
            }
            const int slc = blockIdx.y * STEPS_A + sl;
            uint_t* dst = wx + (size_t)(slc * 256 + bg) * 2048 + l * 4 + 2 * (w & 1);
            #pragma unroll
            for (int i = 0; i < 4; ++i) {
                uint_t d0 = (uint_t)f2bf(g[i][0]) | ((uint_t)f2bf(g[i][1]) << 16);
                uint_t d1 = (uint_t)f2bf(g[i][2]) | ((uint_t)f2bf(g[i][3]) << 16);
                uint2 vv; vv.x = d0; vv.y = d1;
                *(uint2*)(dst + (2 * i + (w >> 1)) * 256) = vv;
            }
            #pragma unroll
            for (int j = 0; j < 4; ++j) {
                int r = 4 * j + prow;
                sx[cur ^ 1][r * SX_STR + pcol] = f2bf(pf[j]);
            }
        }
        __syncthreads();
        cur ^= 1;
    }
}

// ============================================================================
// Kernel B: recurrence. gates = wx(s) + h@Whh ; pointwise ; val = h@Wv+bv
// 256 blocks x 4 waves; wave w owns gate tiles {w, w+4, w+8, w+12}
// (= i,f,g,o for hidden units 16w+m). One barrier per step.
// ============================================================================
__global__ __launch_bounds__(NT, 1)
void podcritic_rec(const float* __restrict__ Whh,
                   const float* __restrict__ Wv, const float* __restrict__ bv,
                   const uint_t* __restrict__ wx,
                   ushort_t* __restrict__ hws, float* __restrict__ cws,
                   float* __restrict__ out, int c0, int first, int last)
{
    __shared__ __align__(16) ushort_t sh[2][NB * SH_STR];
    __shared__ float sval[2][64];

    const int t  = threadIdx.x;
    const int w  = t >> 6;
    const int l  = t & 63;
    const int q  = l >> 4;
    const int m  = l & 15;
    const int bg = blockIdx.x;
    const int b0 = bg * NB;

    short8 whhf[4][2];
    #pragma unroll
    for (int a = 0; a < 4; ++a) {
        int n = (w + 4 * a) * 16 + m;
        #pragma unroll
        for (int kk = 0; kk < 2; ++kk) {
            FragU u;
            #pragma unroll
            for (int j = 0; j < 8; ++j) {
                int k = kk * 32 + q * 8 + j;
                u.u[j] = f2bf(Whh[k * 256 + n]);
            }
            whhf[a][kk] = u.v;
        }
    }
    const float wv  = Wv[16 * w + m];
    const float bvv = bv[0];

    float creg[4], hreg[4] = {0.f, 0.f, 0.f, 0.f};
    if (first) {
        #pragma unroll
        for (int r = 0; r < 4; ++r) creg[r] = 0.f;
        #pragma unroll
        for (int k = 0; k < 4; ++k) {
            int idx = t + 256 * k;
            sh[0][(idx >> 6) * SH_STR + (idx & 63)] = 0;
        }
    } else {
        #pragma unroll
        for (int k = 0; k < 4; ++k) {
            int idx = t + 256 * k;
            sh[0][(idx >> 6) * SH_STR + (idx & 63)] = hws[bg * 1024 + idx];
        }
        float4 cv = *(const float4*)(cws + bg * 1024 + t * 4);
        creg[0] = cv.x; creg[1] = cv.y; creg[2] = cv.z; creg[3] = cv.w;
    }
    __syncthreads();

    // prefetch wx for step 0
    uint2 upf[4];
    {
        const uint_t* p0 = wx + (size_t)(0 * 256 + bg) * 2048 + l * 4 + 2 * (w & 1);
        #pragma unroll
        for (int a = 0; a < 4; ++a) upf[a] = *(const uint2*)(p0 + (2 * a + (w >> 1)) * 256);
    }

    int p = 0;
    for (int sl = 0; sl < CS; ++sl) {
        short8 af0 = *(const short8*)&sh[p][m * SH_STR + q * 8];
        short8 af1 = *(const short8*)&sh[p][m * SH_STR + 32 + q * 8];

        f32x4 g[4];
        #pragma unroll
        for (int a = 0; a < 4; ++a) {
            g[a][0] = bf2f((ushort_t)(upf[a].x & 0xFFFF));
            g[a][1] = bf2f((ushort_t)(upf[a].x >> 16));
            g[a][2] = bf2f((ushort_t)(upf[a].y & 0xFFFF));
            g[a][3] = bf2f((ushort_t)(upf[a].y >> 16));
        }

        uint2 unext[4] = {upf[0], upf[1], upf[2], upf[3]};
        if (sl + 1 < CS) {
            const uint_t* pn = wx + (size_t)((sl + 1) * 256 + bg) * 2048 + l * 4 + 2 * (w & 1);
            #pragma unroll
            for (int a = 0; a < 4; ++a) unext[a] = *(const uint2*)(pn + (2 * a + (w >> 1)) * 256);
        }

        #pragma unroll
        for (int a = 0; a < 4; ++a) {
            g[a] = __builtin_amdgcn_mfma_f32_16x16x32_bf16(af0, whhf[a][0], g[a], 0, 0, 0);
            g[a] = __builtin_amdgcn_mfma_f32_16x16x32_bf16(af1, whhf[a][1], g[a], 0, 0, 0);
        }

        float pv[4];
        #pragma unroll
        for (int r = 0; r < 4; ++r) {
            float gi = fsig(g[0][r]);
            float gf = fsig(g[1][r]);
            float gg = ftanh(g[2][r]);
            float go = fsig(g[3][r]);
            float c  = gf * creg[r] + gi * gg;
            creg[r] = c;
            float h = go * ftanh(c);
            hreg[r] = h;
            sh[p ^ 1][(q * 4 + r) * SH_STR + 16 * w + m] = f2bf(h);
            pv[r] = h * wv;
        }
        #pragma unroll
        for (int mask = 1; mask <= 8; mask <<= 1) {
            #pragma unroll
            for (int r = 0; r < 4; ++r) pv[r] += __shfl_xor(pv[r], mask, 64);
        }
        if (m == 0) {
            #pragma unroll
            for (int r = 0; r < 4; ++r) sval[p][w * 16 + 4 * q + r] = pv[r];
        }
        #pragma unroll
        for (int a = 0; a < 4; ++a) upf[a] = unext[a];

        __syncthreads();

        if (t < 16)
            out[(size_t)(b0 + t) * SS + (c0 + sl)] =
                sval[p][t] + sval[p][16 + t] + sval[p][32 + t] + sval[p][48 + t] + bvv;
        p ^= 1;
    }

    if (!last) {
        #pragma unroll
        for (int k = 0; k < 4; ++k) {
            int idx = t + 256 * k;
            hws[bg * 1024 + idx] = sh[p][(idx >> 6) * SH_STR + (idx & 63)];
        }
        float4 cv; cv.x = creg[0]; cv.y = creg[1]; cv.z = creg[2]; cv.w = creg[3];
        *(float4*)(cws + bg * 1024 + t * 4) = cv;
    } else {
        const int jcol = 16 * w + m;
        #pragma unroll
        for (int r = 0; r < 4; ++r) {
            int row = b0 + q * 4 + r;
            out[BB * SS + row * 64 + jcol]           = hreg[r];
            out[BB * SS + BB * 64 + row * 64 + jcol] = creg[r];
        }
    }
}

// ============================================================================
// Fallback: round-2 fused kernel (used only if ws_size is too small)
// ============================================================================
__global__ __launch_bounds__(NT, 1)
void podcritic_mfma(const float* __restrict__ self_obs,
                    const float* __restrict__ tm_obs,
                    const float* __restrict__ en_obs,
                    const float* __restrict__ cp_obs,
                    const float* __restrict__ W1, const float* __restrict__ b1,
                    const float* __restrict__ W2, const float* __restrict__ b2,
                    const float* __restrict__ Wih, const float* __restrict__ bih,
                    const float* __restrict__ Whh, const float* __restrict__ bhh,
                    const float* __restrict__ Wv, const float* __restrict__ bv,
                    float* __restrict__ out)
{
    __shared__ __align__(16) ushort_t sx[2][NB * SX_STR];
    __shared__ __align__(16) ushort_t sh1[NB * SH1_STR];
    __shared__ __align__(16) ushort_t semb[NB * SEMB_STR];
    __shared__ __align__(16) ushort_t sh[NB * SH_STR];
    __shared__ float sWv[64];

    const int t  = threadIdx.x;
    const int w  = t >> 6;
    const int l  = t & 63;
    const int q  = l >> 4;
    const int m  = l & 15;
    const int b0 = blockIdx.x * NB;

    short8 w1f[4][2];
    short8 w2f[2][8];
    short8 wihf[4][4];
    short8 whhf[4][2];
    float bias1[4], bias2[2], bg[4];

    #pragma unroll
    for (int i = 0; i < 4; ++i) {
        int n = w * 64 + i * 16 + m;
        bias1[i] = b1[n];
        #pragma unroll
        for (int kk = 0; kk < 2; ++kk) {
            FragU u;
            #pragma unroll
            for (int j = 0; j < 8; ++j) {
                int k = kk * 32 + q * 8 + j;
                u.u[j] = f2bf(k < 47 ? W1[k * 256 + n] : 0.f);
            }
            w1f[i][kk] = u.v;
        }
    }
    #pragma unroll
    for (int i = 0; i < 2; ++i) {
        int n = 32 * w + i * 16 + m;
        bias2[i] = b2[n];
        #pragma unroll
        for (int kk = 0; kk < 8; ++kk) {
            FragU u;
            #pragma unroll
            for (int j = 0; j < 8; ++j) {
                int k = kk * 32 + q * 8 + j;
                u.u[j] = f2bf(W2[k * 128 + n]);
            }
            w2f[i][kk] = u.v;
        }
    }
    #pragma unroll
    for (int i = 0; i < 4; ++i) {
        int n = (w + 4 * i) * 16 + m;
        bg[i] = bih[n] + bhh[n];
        #pragma unroll
        for (int kk = 0; kk < 4; ++kk) {
            FragU u;
            #pragma unroll
            for (int j = 0; j < 8; ++j) {
                int k = kk * 32 + q * 8 + j;
                u.u[j] = f2bf(Wih[k * 256 + n]);
            }
            wihf[i][kk] = u.v;
        }
        #pragma unroll
        for (int kk = 0; kk < 2; ++kk) {
            FragU u;
            #pragma unroll
            for (int j = 0; j < 8; ++j) {
                int k = kk * 32 + q * 8 + j;
                u.u[j] = f2bf(Whh[k * 256 + n]);
            }
            whhf[i][kk] = u.v;
        }
    }
    const float bvv = bv[0];
    if (t < 64) sWv[t] = Wv[t];

    for (int idx = t; idx < NB * SH_STR; idx += NT) sh[idx] = 0;

    const int pcol = t & 63;
    const int prow = t >> 6;
    #pragma unroll
    for (int j = 0; j < 4; ++j) {
        int r  = 4 * j + prow;
        int bs = (b0 + r) * SS + 0;
        float v = 0.f;
        if (pcol < 15)      v = self_obs[bs * 15 + pcol];
        else if (pcol < 28) v = tm_obs[bs * 13 + (pcol - 15)];
        else if (pcol < 41) { int kk = pcol - 28;
                              v = 0.5f * (en_obs[(bs * 2) * 13 + kk] + en_obs[(bs * 2) * 13 + 13 + kk]); }
        else if (pcol < 47) v = cp_obs[bs * 6 + (pcol - 41)];
        sx[0][r * SX_STR + pcol] = f2bf(v);
    }
    __syncthreads();

    float creg[4] = {0.f, 0.f, 0.f, 0.f};
    float hreg[4] = {0.f, 0.f, 0.f, 0.f};
    int cur = 0;

    for (int s = 0; s < SS; ++s) {
        float pf[4];
        #pragma unroll
        for (int j = 0; j < 4; ++j) {
            float v = 0.f;
            if (s + 1 < SS) {
                int r  = 4 * j + prow;
                int bs = (b0 + r) * SS + (s + 1);
                if (pcol < 15)      v = self_obs[bs * 15 + pcol];
                else if (pcol < 28) v = tm_obs[bs * 13 + (pcol - 15)];
                else if (pcol < 41) { int kk = pcol - 28;
                                      v = 0.5f * (en_obs[(bs * 2) * 13 + kk] + en_obs[(bs * 2) * 13 + 13 + kk]); }
                else if (pcol < 47) v = cp_obs[bs * 6 + (pcol - 41)];
            }
            pf[j] = v;
        }

        {
            f32x4 c1[4] = {{0,0,0,0},{0,0,0,0},{0,0,0,0},{0,0,0,0}};
            #pragma unroll
            for (int kk = 0; kk < 2; ++kk) {
                short8 a = *(const short8*)&sx[cur][m * SX_STR + kk * 32 + q * 8];
                #pragma unroll
                for (int i = 0; i < 4; ++i)
                    c1[i] = __builtin_amdgcn_mfma_f32_16x16x32_bf16(a, w1f[i][kk], c1[i], 0, 0, 0);
            }
            #pragma unroll
            for (int i = 0; i < 4; ++i) {
                int col = w * 64 + i * 16 + m;
                #pragma unroll
                for (int r = 0; r < 4; ++r)
                    sh1[(q * 4 + r) * SH1_STR + col] = f2bf(fmaxf(c1[i][r] + bias1[i], 0.f));
            }
        }
        __syncthreads();

        {
            f32x4 c2[2] = {{0,0,0,0},{0,0,0,0}};
            #pragma unroll
            for (int kk = 0; kk < 8; ++kk) {
                short8 a = *(const short8*)&sh1[m * SH1_STR + kk * 32 + q * 8];
                #pragma unroll
                for (int i = 0; i < 2; ++i)
                    c2[i] = __builtin_amdgcn_mfma_f32_16x16x32_bf16(a, w2f[i][kk], c2[i], 0, 0, 0);
            }
            #pragma unroll
            for (int i = 0; i < 2; ++i) {
                int col = 32 * w + i * 16 + m;
                #pragma unroll
                for (int r = 0; r < 4; ++r)
                    semb[(q * 4 + r) * SEMB_STR + col] = f2bf(fmaxf(c2[i][r] + bias2[i], 0.f));
            }
        }
        __syncthreads();

        {
            f32x4 g[4];
            #pragma unroll
            for (int i = 0; i < 4; ++i) g[i] = (f32x4){bg[i], bg[i], bg[i], bg[i]};
            #pragma unroll
            for (int kk = 0; kk < 4; ++kk) {
                short8 a = *(const short8*)&semb[m * SEMB_STR + kk * 32 + q * 8];
                #pragma unroll
                for (int i = 0; i < 4; ++i)
                    g[i] = __builtin_amdgcn_mfma_f32_16x16x32_bf16(a, wihf[i][kk], g[i], 0, 0, 0);
            }
            #pragma unroll
            for (int kk = 0; kk < 2; ++kk) {
                short8 a = *(const short8*)&sh[m * SH_STR + kk * 32 + q * 8];
                #pragma unroll
                for (int i = 0; i < 4; ++i)
                    g[i] = __builtin_amdgcn_mfma_f32_16x16x32_bf16(a, whhf[i][kk], g[i], 0, 0, 0);
            }
            const int jcol = 16 * w + m;
            #pragma unroll
            for (int r = 0; r < 4; ++r) {
                float gi = fsig(g[0][r]);
                float gf = fsig(g[1][r]);
                float gg = ftanh(g[2][r]);
                float go = fsig(g[3][r]);
                float c  = gf * creg[r] + gi * gg;
                creg[r] = c;
                float h = go * ftanh(c);
                hreg[r] = h;
                sh[(q * 4 + r) * SH_STR + jcol] = f2bf(h);
            }
            #pragma unroll
            for (int j = 0; j < 4; ++j) {
                int r = 4 * j + prow;
                sx[cur ^ 1][r * SX_STR + pcol] = f2bf(pf[j]);
            }
        }
        __syncthreads();

        {
            int r = t >> 4, pp = t & 15;
            const ushort_t* hp = &sh[r * SH_STR + pp * 4];
            float pv = 0.f;
            #pragma unroll
            for (int j = 0; j < 4; ++j) pv += bf2f(hp[j]) * sWv[pp * 4 + j];
            pv += __shfl_xor(pv, 1, 16);
            pv += __shfl_xor(pv, 2, 16);
            pv += __shfl_xor(pv, 4, 16);
            pv += __shfl_xor(pv, 8, 16);
            if (pp == 0) out[(b0 + r) * SS + s] = pv + bvv;
        }
        cur ^= 1;
    }

    {
        const int jcol = 16 * w + m;
        #pragma unroll
        for (int r = 0; r < 4; ++r) {
            int row = b0 + q * 4 + r;
            out[BB * SS + row * 64 + jcol]           = hreg[r];
            out[BB * SS + BB * 64 + row * 64 + jcol] = creg[r];
        }
    }
}

extern "C" void kernel_launch(void* const* d_in, const int* in_sizes, int n_in,
                              void* d_out, int out_size, void* d_ws, size_t ws_size,
                              hipStream_t stream) {
    const float* self_obs = (const float*)d_in[0];
    const float* tm_obs   = (const float*)d_in[1];
    const float* en_obs   = (const float*)d_in[2];
    const float* cp_obs   = (const float*)d_in[3];
    const float* W1  = (const float*)d_in[4];
    const float* b1  = (const float*)d_in[5];
    const float* W2  = (const float*)d_in[6];
    const float* b2  = (const float*)d_in[7];
    const float* Wih = (const float*)d_in[8];
    const float* bih = (const float*)d_in[9];
    const float* Whh = (const float*)d_in[10];
    const float* bhh = (const float*)d_in[11];
    const float* Wv  = (const float*)d_in[12];
    const float* bv  = (const float*)d_in[13];
    float* out = (float*)d_out;

    const size_t wx_bytes = (size_t)CS * 256 * 2048 * 4;  // 67,108,864
    const size_t h_bytes  = 256 * 1024 * sizeof(ushort_t); // 524,288
    const size_t c_bytes  = 256 * 1024 * sizeof(float);    // 1,048,576
    const size_t need     = wx_bytes + h_bytes + c_bytes;

    if (ws_size >= need) {
        uint_t*   wx  = (uint_t*)d_ws;
        ushort_t* hws = (ushort_t*)((char*)d_ws + wx_bytes);
        float*    cws = (float*)((char*)d_ws + wx_bytes + h_bytes);
        for (int c = 0; c < NCH; ++c) {
            podcritic_enc<<<dim3(256, NSUB), NT, 0, stream>>>(
                self_obs, tm_obs, en_obs, cp_obs,
                W1, b1, W2, b2, Wih, bih, bhh, wx, c * CS);
            podcritic_rec<<<256, NT, 0, stream>>>(
                Whh, Wv, bv, wx, hws, cws, out, c * CS,
                (c == 0) ? 1 : 0, (c == NCH - 1) ? 1 : 0);
        }
    } else {
        podcritic_mfma<<<BB / NB, NT, 0, stream>>>(
            self_obs, tm_obs, en_obs, cp_obs,
            W1, b1, W2, b2, Wih, bih, Whh, bhh, Wv, bv, out);
    }
}